// Round 1
// baseline (78.317 us; speedup 1.0000x reference)
//
#include <hip/hip_runtime.h>

// Problem constants (reference: B=8, E=16, H=256, W=256)
#define NB 8
#define NE 16
#define HW (256 * 256)        // pixels per sample = 65536
#define HW4 (HW / 4)          // float4 groups per sample = 16384
#define NPIX (NB * HW)        // total pixels = 524288
#define NT4 (NPIX / 4)        // total float4 pixel-groups = 131072
#define NTHR (NT4 / 2)        // 65536 threads, 2 groups each (P=2 pipeline)
#define NBLK 256              // K1 grid = NTHR / 256 -> 1 block/CU

// val(pixel) = mean_e |f_e - o| - 0.5 * mean_{e,e'} |f_e - f_e'|
//            = (1/16) * S1 - (1/256) * S2   (S2 = unordered-pair sum)
// out = (1/NPIX) * sum over pixels of val
//
// Mandatory traffic: 32 MiB fore + 2 MiB obs read exactly once -> 5.7 us
// floor at 6.3 TB/s. K1 is P=2 software-pipelined: batch-0 loads, batch-1
// loads, THEN batch-0 compute -> compiler emits vmcnt(18) so compute of
// group 0 overlaps group 1's in-flight loads (kills the compute tail of
// the old one-shot version). Deterministic two-kernel reduction kept
// (atomics measured 5-20us in earlier rounds).

__device__ __forceinline__ float crps_group(const float v[NE][4], const float o[4]) {
    float acc = 0.0f;
#pragma unroll
    for (int c = 0; c < 4; ++c) {
        float s1 = 0.0f;
#pragma unroll
        for (int e = 0; e < NE; ++e)
            s1 += fabsf(v[e][c] - o[c]);
        float s2 = 0.0f;
#pragma unroll
        for (int i = 0; i < NE; ++i)
#pragma unroll
            for (int j = i + 1; j < NE; ++j)
                s2 += fabsf(v[i][c] - v[j][c]);
        acc += s1 * (1.0f / NE) - s2 * (1.0f / (NE * NE));
    }
    return acc;
}

// (256,1): allow up to 512 VGPR -> no spill for the ~170-reg double batch.
__global__ __launch_bounds__(256, 1) void crps_partial_kernel(
    const float* __restrict__ fore,   // [B, E, HW]
    const float* __restrict__ obs,    // [B, HW]
    float* __restrict__ partial)      // [NBLK]
{
    const int t  = blockIdx.x * 256 + threadIdx.x;   // 0 .. NTHR-1
    const int g0 = t;              // groups 0..65535     (b in 0..3)
    const int g1 = t + NTHR;       // groups 65536..131071 (b in 4..7)
    const int b0 = g0 >> 14, p0 = g0 & (HW4 - 1);    // HW4 = 2^14
    const int b1 = g1 >> 14, p1 = g1 & (HW4 - 1);

    const float4* fore4 = reinterpret_cast<const float4*>(fore);
    const float4* obs4  = reinterpret_cast<const float4*>(obs);

    float va[NE][4], vb[NE][4];
    float oa[4], ob[4];

    // Issue order matters for vmcnt semantics: ALL of batch 0 first, then
    // ALL of batch 1. Compute of batch 0 then only waits for the oldest 17
    // loads (vmcnt(18)) while batch 1 streams in behind it.
#pragma unroll
    for (int e = 0; e < NE; ++e) {
        float4 x = fore4[(size_t)(b0 * NE + e) * HW4 + p0];
        va[e][0] = x.x; va[e][1] = x.y; va[e][2] = x.z; va[e][3] = x.w;
    }
    {
        float4 y = obs4[(size_t)b0 * HW4 + p0];
        oa[0] = y.x; oa[1] = y.y; oa[2] = y.z; oa[3] = y.w;
    }
#pragma unroll
    for (int e = 0; e < NE; ++e) {
        float4 x = fore4[(size_t)(b1 * NE + e) * HW4 + p1];
        vb[e][0] = x.x; vb[e][1] = x.y; vb[e][2] = x.z; vb[e][3] = x.w;
    }
    {
        float4 y = obs4[(size_t)b1 * HW4 + p1];
        ob[0] = y.x; ob[1] = y.y; ob[2] = y.z; ob[3] = y.w;
    }

    float acc = crps_group(va, oa);
    acc += crps_group(vb, ob);

    // 64-lane shuffle reduction
#pragma unroll
    for (int off = 32; off > 0; off >>= 1)
        acc += __shfl_down(acc, off);

    __shared__ float smem[4];          // 256 threads = 4 waves
    const int lane = threadIdx.x & 63;
    const int wave = threadIdx.x >> 6;
    if (lane == 0) smem[wave] = acc;
    __syncthreads();
    if (threadIdx.x == 0)
        partial[blockIdx.x] = smem[0] + smem[1] + smem[2] + smem[3];
}

// Single-wave finisher: 64 lanes x float4 = 256 partials. No LDS, no sync.
__global__ __launch_bounds__(64) void crps_final_kernel(
    const float* __restrict__ partial,  // [NBLK]
    float* __restrict__ out)            // [1]
{
    const float4 p = reinterpret_cast<const float4*>(partial)[threadIdx.x];
    float acc = (p.x + p.y) + (p.z + p.w);
#pragma unroll
    for (int off = 32; off > 0; off >>= 1)
        acc += __shfl_down(acc, off);
    if (threadIdx.x == 0)
        out[0] = acc * (1.0f / NPIX);
}

extern "C" void kernel_launch(void* const* d_in, const int* in_sizes, int n_in,
                              void* d_out, int out_size, void* d_ws, size_t ws_size,
                              hipStream_t stream) {
    const float* fore = (const float*)d_in[0];   // [8,16,256,256] f32
    const float* obs  = (const float*)d_in[1];   // [8,256,256] f32
    float* out     = (float*)d_out;
    float* partial = (float*)d_ws;               // 256 floats of scratch

    crps_partial_kernel<<<NBLK, 256, 0, stream>>>(fore, obs, partial);
    crps_final_kernel<<<1, 64, 0, stream>>>(partial, out);
}

// Round 2
// 77.793 us; speedup vs baseline: 1.0067x; 1.0067x over previous
//
#include <hip/hip_runtime.h>

// Problem constants (reference: B=8, E=16, H=256, W=256)
#define NB 8
#define NE 16
#define HW (256 * 256)        // pixels per sample = 65536
#define HW4 (HW / 4)          // float4 groups per sample = 16384
#define NPIX (NB * HW)        // total pixels = 524288
#define NT4 (NPIX / 4)        // total float4 pixel-groups = 131072
#define NBLK 512              // K1 grid (NT4 / 256) -> 2 blocks/CU, 8 waves/CU

// val(pixel) = mean_e |f_e - o| - 0.5 * mean_{e,e'} |f_e - f_e'|
//            = (1/16) * S1 - (1/256) * S2   (S2 = unordered-pair sum)
// out = (1/NPIX) * sum over pixels of val
//
// R1 post-mortem: P=2 pipeline + launch_bounds(256,1) dropped occupancy to
// 1 wave/SIMD and regressed ~3.4us kernel-side (total 78.3 with cheaper
// fills). Reverted to the R0 structure: one float4-group per thread,
// ~90 VGPR -> 8 waves/CU, 17x16B loads in flight per lane. TLP (8 waves)
// hides the ~900cyc HBM latency better than the 2-batch ILP chain did.
// Mandatory traffic 34 MiB read-once -> 5.7us floor; K1 measured ~6-7us.

__global__ __launch_bounds__(256) void crps_partial_kernel(
    const float* __restrict__ fore,   // [B, E, HW]
    const float* __restrict__ obs,    // [B, HW]
    float* __restrict__ partial)      // [NBLK]
{
    const int idx = blockIdx.x * blockDim.x + threadIdx.x;   // 0 .. NT4-1
    const int b  = idx >> 14;          // idx / HW4   (HW4 = 2^14)
    const int p4 = idx & (HW4 - 1);

    const float4* fore4 = reinterpret_cast<const float4*>(fore);
    const float4* obs4  = reinterpret_cast<const float4*>(obs);

    // 16 ensemble members, 16B/lane coalesced loads (1KB per wave-instr).
    // All 17 loads issue before first use -> ~17KB in flight per wave,
    // 8 waves/CU -> ~136KB/CU outstanding, ample to cover HBM latency.
    float v[NE][4];
#pragma unroll
    for (int e = 0; e < NE; ++e) {
        float4 t = fore4[(size_t)(b * NE + e) * HW4 + p4];
        v[e][0] = t.x; v[e][1] = t.y; v[e][2] = t.z; v[e][3] = t.w;
    }
    float4 ot = obs4[(size_t)b * HW4 + p4];
    float o[4] = { ot.x, ot.y, ot.z, ot.w };

    // 4 components independent -> 4-way ILP on the add chains.
    // |a-b| costs 2 VALU (v_sub + abs-modifier on the consuming v_add);
    // ~1100 VALU/thread -> ~2200 cyc/wave, fully hidden under memory.
    float acc = 0.0f;
#pragma unroll
    for (int c = 0; c < 4; ++c) {
        float s1 = 0.0f;
#pragma unroll
        for (int e = 0; e < NE; ++e)
            s1 += fabsf(v[e][c] - o[c]);
        float s2 = 0.0f;
#pragma unroll
        for (int i = 0; i < NE; ++i)
#pragma unroll
            for (int j = i + 1; j < NE; ++j)
                s2 += fabsf(v[i][c] - v[j][c]);
        acc += s1 * (1.0f / NE) - s2 * (1.0f / (NE * NE));
    }

    // Wave (64-lane) shuffle reduction
#pragma unroll
    for (int off = 32; off > 0; off >>= 1)
        acc += __shfl_down(acc, off);

    __shared__ float smem[4];          // 256 threads = 4 waves
    const int lane = threadIdx.x & 63;
    const int wave = threadIdx.x >> 6;
    if (lane == 0) smem[wave] = acc;
    __syncthreads();
    if (threadIdx.x == 0)
        partial[blockIdx.x] = smem[0] + smem[1] + smem[2] + smem[3];
}

// Single-wave finisher: 64 lanes x 2 float4 = 512 partials. No LDS, no sync.
__global__ __launch_bounds__(64) void crps_final_kernel(
    const float* __restrict__ partial,  // [NBLK]
    float* __restrict__ out)            // [1]
{
    const float4* p4 = reinterpret_cast<const float4*>(partial);
    const float4 a = p4[threadIdx.x];
    const float4 b = p4[threadIdx.x + 64];
    float acc = ((a.x + a.y) + (a.z + a.w)) + ((b.x + b.y) + (b.z + b.w));
#pragma unroll
    for (int off = 32; off > 0; off >>= 1)
        acc += __shfl_down(acc, off);
    if (threadIdx.x == 0)
        out[0] = acc * (1.0f / NPIX);
}

extern "C" void kernel_launch(void* const* d_in, const int* in_sizes, int n_in,
                              void* d_out, int out_size, void* d_ws, size_t ws_size,
                              hipStream_t stream) {
    const float* fore = (const float*)d_in[0];   // [8,16,256,256] f32
    const float* obs  = (const float*)d_in[1];   // [8,256,256] f32
    float* out     = (float*)d_out;
    float* partial = (float*)d_ws;               // 512 floats of scratch

    crps_partial_kernel<<<NBLK, 256, 0, stream>>>(fore, obs, partial);
    crps_final_kernel<<<1, 64, 0, stream>>>(partial, out);
}